// Round 1
// baseline (122.185 us; speedup 1.0000x reference)
//
#include <hip/hip_runtime.h>
#include <math.h>

#define N_ROWS 1024
#define M_ROWS 1024
#define DDIM   512
#define BK     64
#define NCHUNK (DDIM / BK)   // 8

// ---------------- row-norm kernel: ws[0..1023] = ||z_n||^2, ws[1024..2047] = ||zpr_m||^2
__global__ __launch_bounds__(256) void norms_kernel(const float* __restrict__ z,
                                                    const float* __restrict__ zpr,
                                                    float* __restrict__ norms) {
    const int wid  = (blockIdx.x * 256 + threadIdx.x) >> 6;   // one wave per row
    const int lane = threadIdx.x & 63;
    const float* src = (wid < N_ROWS) ? (z + (size_t)wid * DDIM)
                                      : (zpr + (size_t)(wid - N_ROWS) * DDIM);
    const float4* s4 = (const float4*)src;
    float4 a = s4[lane];
    float4 b = s4[lane + 64];
    float s = a.x*a.x + a.y*a.y + a.z*a.z + a.w*a.w
            + b.x*b.x + b.y*b.y + b.z*b.z + b.w*b.w;
#pragma unroll
    for (int off = 32; off > 0; off >>= 1) s += __shfl_down(s, off);
    if (lane == 0) norms[wid] = s;
}

// ---------------- main kernel: 64x64 tile per block, 4x4 per thread
// LDS layout: [d][row] transposed, XOR-swizzled: word(d,n) = d*64 + (n ^ (4*(d>>2)))
//  - compute reads: ds_read_b128, conflict-free (verified bank math)
//  - staging writes: 2-way conflicts only (free per m136)
__global__ __launch_bounds__(256) void dist_kernel(const float* __restrict__ z,
                                                   const float* __restrict__ zpr,
                                                   const float* __restrict__ norms,
                                                   float* __restrict__ out) {
    __shared__ float lz[BK * 64];
    __shared__ float lp[BK * 64];

    const int t  = threadIdx.x;
    const int bn = blockIdx.x & 15;
    const int bm = blockIdx.x >> 4;
    const int n_base = bn * 64;
    const int m_base = bm * 64;

    // staging coords: thread loads float4 at local (row = sr+16p, d = 4*su..+3)
    const int su = t & 15;
    const int sr = t >> 4;
    // compute coords: n0 = 4*tn (varies fastest across lanes -> coalesced stores),
    //                 m0 = 4*tm
    const int tn = t & 15;
    const int tm = t >> 4;

    float l1a[4][4];
    float l2a[4][4];
#pragma unroll
    for (int j = 0; j < 4; ++j)
#pragma unroll
        for (int i = 0; i < 4; ++i) { l1a[j][i] = 0.f; l2a[j][i] = 0.f; }

    const float* zg = z   + (size_t)(n_base + sr) * DDIM + 4 * su;
    const float* pg = zpr + (size_t)(m_base + sr) * DDIM + 4 * su;

    float4 rz[4], rp[4];
    // prefetch chunk 0
#pragma unroll
    for (int p = 0; p < 4; ++p) {
        rz[p] = *(const float4*)(zg + (size_t)(16 * p) * DDIM);
        rp[p] = *(const float4*)(pg + (size_t)(16 * p) * DDIM);
    }

    for (int kc = 0; kc < NCHUNK; ++kc) {
        // regs -> LDS (swizzled transpose)
#pragma unroll
        for (int p = 0; p < 4; ++p) {
            const int nl = sr + 16 * p;
            const int sw = nl ^ (4 * su);
            lz[(4*su + 0)*64 + sw] = rz[p].x;
            lz[(4*su + 1)*64 + sw] = rz[p].y;
            lz[(4*su + 2)*64 + sw] = rz[p].z;
            lz[(4*su + 3)*64 + sw] = rz[p].w;
            lp[(4*su + 0)*64 + sw] = rp[p].x;
            lp[(4*su + 1)*64 + sw] = rp[p].y;
            lp[(4*su + 2)*64 + sw] = rp[p].z;
            lp[(4*su + 3)*64 + sw] = rp[p].w;
        }
        __syncthreads();

        // prefetch next chunk into regs; vmcnt wait lands before next LDS write
        if (kc + 1 < NCHUNK) {
            const float* zgn = zg + (kc + 1) * BK;
            const float* pgn = pg + (kc + 1) * BK;
#pragma unroll
            for (int p = 0; p < 4; ++p) {
                rz[p] = *(const float4*)(zgn + (size_t)(16 * p) * DDIM);
                rp[p] = *(const float4*)(pgn + (size_t)(16 * p) * DDIM);
            }
        }

        // compute 64 d's
        for (int d4 = 0; d4 < 16; ++d4) {
            const int xd = 4 * d4;
            const int ia = (4 * tn) ^ xd;
            const int ib = (4 * tm) ^ xd;
#pragma unroll
            for (int k = 0; k < 4; ++k) {
                const float4 a = *(const float4*)&lz[(4*d4 + k)*64 + ia];
                const float4 b = *(const float4*)&lp[(4*d4 + k)*64 + ib];
                const float av[4] = {a.x, a.y, a.z, a.w};
                const float bv[4] = {b.x, b.y, b.z, b.w};
#pragma unroll
                for (int j = 0; j < 4; ++j)
#pragma unroll
                    for (int i = 0; i < 4; ++i) {
                        const float diff = av[i] - bv[j];
                        l1a[j][i] += fabsf(diff);                    // abs is free VOP3 modifier
                        l2a[j][i] = fmaf(diff, diff, l2a[j][i]);
                    }
            }
        }
        __syncthreads();
    }

    // epilogue: l2 = sqrt(l2sq); dp = (||z||^2 + ||zpr||^2 - l2sq) / 2
    const int n0g = n_base + 4 * tn;
    const int m0g = m_base + 4 * tm;
    float znv[4], pnv[4];
#pragma unroll
    for (int i = 0; i < 4; ++i) znv[i] = norms[n0g + i];
#pragma unroll
    for (int j = 0; j < 4; ++j) pnv[j] = norms[N_ROWS + m0g + j];

#pragma unroll
    for (int j = 0; j < 4; ++j) {
        float l2v[4], dpv[4];
#pragma unroll
        for (int i = 0; i < 4; ++i) {
            const float s = l2a[j][i];
            dpv[i] = 0.5f * (znv[i] + pnv[j] - s);
            l2v[i] = sqrtf(s);
        }
        float4* op = (float4*)(out + ((size_t)(m0g + j) * N_ROWS + n0g) * 3);
        op[0] = make_float4(l1a[j][0], l2v[0], dpv[0], l1a[j][1]);
        op[1] = make_float4(l2v[1],    dpv[1], l1a[j][2], l2v[2]);
        op[2] = make_float4(dpv[2],    l1a[j][3], l2v[3], dpv[3]);
    }
}

extern "C" void kernel_launch(void* const* d_in, const int* in_sizes, int n_in,
                              void* d_out, int out_size, void* d_ws, size_t ws_size,
                              hipStream_t stream) {
    const float* z   = (const float*)d_in[0];
    const float* zpr = (const float*)d_in[1];
    float* out   = (float*)d_out;
    float* norms = (float*)d_ws;   // 2048 floats

    norms_kernel<<<(N_ROWS + M_ROWS) / 4, 256, 0, stream>>>(z, zpr, norms);
    dist_kernel<<<256, 256, 0, stream>>>(z, zpr, norms, out);
}

// Round 3
// 100.337 us; speedup vs baseline: 1.2178x; 1.2178x over previous
//
#include <hip/hip_runtime.h>
#include <math.h>

#define NROWS 1024
#define DDIM  512

typedef _Float16 h2 __attribute__((ext_vector_type(2)));
typedef unsigned int u32;

__device__ __forceinline__ h2 bch2(u32 u){ return __builtin_bit_cast(h2, u); }
__device__ __forceinline__ u32 pkrtz(float x, float y){
    return __builtin_bit_cast(u32, __builtin_amdgcn_cvt_pkrtz(x, y));
}
__device__ __forceinline__ h2 habs2(h2 x){
    u32 u = __builtin_bit_cast(u32, x) & 0x7FFF7FFFu;
    return __builtin_bit_cast(h2, u);
}

#if __has_builtin(__builtin_amdgcn_fdot2)
#define FDOT2(a,b,c) __builtin_amdgcn_fdot2((a),(b),(c),false)
#else
__device__ __forceinline__ float fdot2_sw(h2 a, h2 b, float c){
    return c + (float)a[0]*(float)b[0] + (float)a[1]*(float)b[1];
}
#define FDOT2(a,b,c) fdot2_sw((a),(b),(c))
#endif

// One fused kernel. 256 blocks (16x16 tiles of 64x64), 512 threads = 8 waves/CU.
// Group g = t>>8 handles k-range [g*256, g*256+256) in 4 chunks of 64.
// LDS f16 transposed layout per group/array: word(k2, n) = k2*64 + n (half2 of k,k+1).
// Reads: a-frag b128 (4 n's, 2-way banks = free), b-frag b128 broadcast.
// End: group1 LDS-reduces its (l1,l2sq) partials into group0; norms accumulated
// in-kernel from the same f16 tiles (consistent precision for the dp identity).
__global__ __launch_bounds__(512) void fused_kernel(const float* __restrict__ z,
                                                    const float* __restrict__ zpr,
                                                    float* __restrict__ out){
    __shared__ u32 smem[9344];
    u32*   stg = smem;                    // [g][arr][k2:32][n:64]  (32 KB)
    float* red = (float*)smem;            // alias after k-loop: [256][32] f32
    float* nzp = (float*)(smem + 8192);   // [8][64] partial ||z||^2
    float* npp = nzp + 512;               // [8][64] partial ||zpr||^2
    float* nzf = npp + 512;               // [64] final
    float* npf = nzf + 64;                // [64] final

    const int t  = threadIdx.x;
    const int g  = t >> 8;
    const int q  = t & 255;
    const int bn = blockIdx.x & 15;
    const int bm = blockIdx.x >> 4;
    const int n_base = bn * 64, m_base = bm * 64;

    const int r   = q >> 2;      // staging row 0..63
    const int kq  = q & 3;       // staging float4 slot (coalesced: 4 lanes = 64B)
    const int tn  = q & 15;      // compute n-quad
    const int tm  = q >> 4;      // compute m-quad
    const int nn  = q & 63;      // norm row
    const int kq2 = q >> 6;      // norm k2-octet

    const float* gz = z   + (size_t)(n_base + r) * DDIM + 4*kq + g*256;
    const float* gp = zpr + (size_t)(m_base + r) * DDIM + 4*kq + g*256;

    float l1a[4][4], l2a[4][4];
#pragma unroll
    for (int j = 0; j < 4; ++j)
#pragma unroll
        for (int i = 0; i < 4; ++i){ l1a[j][i] = 0.f; l2a[j][i] = 0.f; }
    float nzacc = 0.f, npacc = 0.f;

    const h2 one2 = {(_Float16)1.0f, (_Float16)1.0f};

    float4 pre[8];
#pragma unroll
    for (int p = 0; p < 4; ++p){
        pre[p]     = *(const float4*)(gz + 16*p);
        pre[4 + p] = *(const float4*)(gp + 16*p);
    }

    u32* wz = stg + g*4096 + (2*kq)*64 + r;          // + (8p+c)*64
    u32* wp = wz + 2048;
    const u32* az = stg + g*4096 + 4*tn;             // + 64*k2
    const u32* bz = stg + g*4096 + 2048 + 4*tm;
    const u32* na = stg + g*4096 + (8*kq2)*64 + nn;  // + 64*w
    const u32* nb = na + 2048;

    for (int ck = 0; ck < 4; ++ck){
        // stage current chunk (fp32 regs -> f16 LDS)
#pragma unroll
        for (int p = 0; p < 4; ++p){
            float4 v = pre[p];
            wz[(8*p    )*64] = pkrtz(v.x, v.y);
            wz[(8*p + 1)*64] = pkrtz(v.z, v.w);
            float4 w = pre[4 + p];
            wp[(8*p    )*64] = pkrtz(w.x, w.y);
            wp[(8*p + 1)*64] = pkrtz(w.z, w.w);
        }
        __syncthreads();

        // prefetch next chunk into regs
        if (ck < 3){
#pragma unroll
            for (int p = 0; p < 4; ++p){
                pre[p]     = *(const float4*)(gz + (ck+1)*64 + 16*p);
                pre[4 + p] = *(const float4*)(gp + (ck+1)*64 + 16*p);
            }
        }

        // main math: 32 k2-steps, 16 pairs each
#pragma unroll 8
        for (int k2 = 0; k2 < 32; ++k2){
            uint4 aw = *(const uint4*)(az + 64*k2);
            uint4 bw = *(const uint4*)(bz + 64*k2);
            h2 av[4] = {bch2(aw.x), bch2(aw.y), bch2(aw.z), bch2(aw.w)};
            h2 bv[4] = {bch2(bw.x), bch2(bw.y), bch2(bw.z), bch2(bw.w)};
#pragma unroll
            for (int j = 0; j < 4; ++j)
#pragma unroll
                for (int i = 0; i < 4; ++i){
                    h2 d = av[i] - bv[j];               // v_pk_add_f16 (neg)
                    l1a[j][i] = FDOT2(habs2(d), one2, l1a[j][i]);
                    l2a[j][i] = FDOT2(d, d, l2a[j][i]);
                }
        }

        // norm mini-pass over this chunk (reads same f16 tiles)
#pragma unroll
        for (int w = 0; w < 8; ++w){
            h2 xa = bch2(na[64*w]);
            h2 xb = bch2(nb[64*w]);
            nzacc = FDOT2(xa, xa, nzacc);
            npacc = FDOT2(xb, xb, npacc);
        }
        __syncthreads();
    }

    // ---- cross-group reduction ----
    nzp[(g*4 + kq2)*64 + nn] = nzacc;
    npp[(g*4 + kq2)*64 + nn] = npacc;
    if (g == 1){
        float* rp = red + q*32;
#pragma unroll
        for (int j = 0; j < 4; ++j){
            *(float4*)(rp + 4*j)      = make_float4(l1a[j][0], l1a[j][1], l1a[j][2], l1a[j][3]);
            *(float4*)(rp + 16 + 4*j) = make_float4(l2a[j][0], l2a[j][1], l2a[j][2], l2a[j][3]);
        }
    }
    __syncthreads();

    if (t < 128){
        const float* src = (t < 64) ? nzp : npp;
        float s = 0.f;
#pragma unroll
        for (int u = 0; u < 8; ++u) s += src[u*64 + (t & 63)];
        ((t < 64) ? nzf : npf)[t & 63] = s;
    }
    __syncthreads();

    if (g == 0){
        const float* rp = red + q*32;
#pragma unroll
        for (int j = 0; j < 4; ++j){
            float4 p1 = *(const float4*)(rp + 4*j);
            float4 p2 = *(const float4*)(rp + 16 + 4*j);
            l1a[j][0] += p1.x; l1a[j][1] += p1.y; l1a[j][2] += p1.z; l1a[j][3] += p1.w;
            l2a[j][0] += p2.x; l2a[j][1] += p2.y; l2a[j][2] += p2.z; l2a[j][3] += p2.w;
        }
        float4 nz4 = *(const float4*)&nzf[4*tn];
        float4 np4 = *(const float4*)&npf[4*tm];
        const float znv[4] = {nz4.x, nz4.y, nz4.z, nz4.w};
        const float pnv[4] = {np4.x, np4.y, np4.z, np4.w};
        const int n0g = n_base + 4*tn;
        const int m0g = m_base + 4*tm;
#pragma unroll
        for (int j = 0; j < 4; ++j){
            float l2v[4], dpv[4];
#pragma unroll
            for (int i = 0; i < 4; ++i){
                const float s = l2a[j][i];
                dpv[i] = 0.5f * (znv[i] + pnv[j] - s);
                l2v[i] = sqrtf(s);
            }
            float4* op = (float4*)(out + ((size_t)(m0g + j) * NROWS + n0g) * 3);
            op[0] = make_float4(l1a[j][0], l2v[0], dpv[0], l1a[j][1]);
            op[1] = make_float4(l2v[1],    dpv[1], l1a[j][2], l2v[2]);
            op[2] = make_float4(dpv[2],    l1a[j][3], l2v[3], dpv[3]);
        }
    }
}

extern "C" void kernel_launch(void* const* d_in, const int* in_sizes, int n_in,
                              void* d_out, int out_size, void* d_ws, size_t ws_size,
                              hipStream_t stream) {
    const float* z   = (const float*)d_in[0];
    const float* zpr = (const float*)d_in[1];
    float* out = (float*)d_out;
    fused_kernel<<<256, 512, 0, stream>>>(z, zpr, out);
}

// Round 4
// 93.402 us; speedup vs baseline: 1.3082x; 1.0742x over previous
//
#include <hip/hip_runtime.h>
#include <math.h>

typedef unsigned int u32;
typedef _Float16 h2 __attribute__((ext_vector_type(2)));
typedef _Float16 h8 __attribute__((ext_vector_type(8)));
typedef float f32x4 __attribute__((ext_vector_type(4)));

__device__ __forceinline__ h2 bch2(u32 u){ return __builtin_bit_cast(h2, u); }
__device__ __forceinline__ u32 pkrtz(float x, float y){
    return __builtin_bit_cast(u32, __builtin_amdgcn_cvt_pkrtz(x, y));
}
__device__ __forceinline__ h2 habs2(h2 x){
    return __builtin_bit_cast(h2, __builtin_bit_cast(u32, x) & 0x7FFF7FFFu);
}

// 512 blocks x 512 threads (launch_bounds(512,4) -> 2 blocks/CU, 16 waves/CU).
// Tile: 32(n) x 64(m). K-split: group g = t>>8 handles k in [g*256, g*256+256),
// 4 chunks of 64. LDS f16 tiles [k2][row]. Hot loop: 3 VOP3P ops per pair-k2
// (pk_add diff, and abs, pk_add acc) -- l1 only. dp via MFMA f16 on the same
// tiles (idle matrix pipe); l2^2 = nz + np - 2*dp in epilogue.
__global__ __launch_bounds__(512, 4) void fused_kernel(const float* __restrict__ z,
                                                       const float* __restrict__ zpr,
                                                       float* __restrict__ out){
    __shared__ u32 smem[6880];
    // word offsets: stgZ [2][32][32] @0 (2048); stgP [2][32][64] @2048 (4096)
    // overlay after final barrier: dpL f32 [2][32][65] @0 (4160); l1b [256][8] @4224 (2048)
    // nzp @6272 (256); npp @6528 (256); nzf @6784 (32); npf @6816 (64)
    const int t    = threadIdx.x;
    const int g    = t >> 8;
    const int q    = t & 255;
    const int lane = t & 63;
    const int w    = (q >> 6) & 3;      // wave within group

    const int bn = blockIdx.x & 31;
    const int bm = blockIdx.x >> 5;
    const int n_base = bn * 32, m_base = bm * 64;

    u32* stgZ = smem + g * 1024;
    u32* stgP = smem + 2048 + g * 2048;

    // staging coords
    const int rz = q >> 3, sz = q & 7;   // z: row 0..31, f4-slots {sz, sz+8}
    const int rp = q >> 2, sp = q & 3;   // zpr: row 0..63, f4-slots {sp,sp+4,sp+8,sp+12}
    // main-loop coords: 4(n) x 2(m) micro-tile
    const int tn = q & 7;                // n0 = 4*tn
    const int tm = q >> 3;               // m0 = 2*tm
    // norm coords
    const int nrow_z = q & 31, noct  = (q >> 5) & 3;  // used when q<128
    const int nrow_p = q & 63, nhalf = (q >> 6) & 1;  // used when q>=128

    const float* gz = z   + (size_t)(n_base + rz) * 512 + g * 256 + 4 * sz;
    const float* gp = zpr + (size_t)(m_base + rp) * 512 + g * 256 + 4 * sp;

    float4 preZ[2], preP[4];
    preZ[0] = *(const float4*)(gz);
    preZ[1] = *(const float4*)(gz + 32);
#pragma unroll
    for (int u2 = 0; u2 < 4; ++u2) preP[u2] = *(const float4*)(gp + 16 * u2);

    float l1f[2][4];
#pragma unroll
    for (int j = 0; j < 2; ++j)
#pragma unroll
        for (int i = 0; i < 4; ++i) l1f[j][i] = 0.f;
    f32x4 dpacc[2];
    dpacc[0] = (f32x4)(0.f);
    dpacc[1] = (f32x4)(0.f);
    float nzacc = 0.f, npacc = 0.f;

    for (int ck = 0; ck < 4; ++ck){
        // stage fp32 regs -> f16 LDS tiles
        {
            float4 v = preZ[0];
            stgZ[(2*sz+0)*32 + rz]     = pkrtz(v.x, v.y);
            stgZ[(2*sz+1)*32 + rz]     = pkrtz(v.z, v.w);
            v = preZ[1];
            stgZ[(2*(sz+8)+0)*32 + rz] = pkrtz(v.x, v.y);
            stgZ[(2*(sz+8)+1)*32 + rz] = pkrtz(v.z, v.w);
#pragma unroll
            for (int u2 = 0; u2 < 4; ++u2){
                float4 p = preP[u2];
                const int s = sp + 4 * u2;
                stgP[(2*s+0)*64 + rp] = pkrtz(p.x, p.y);
                stgP[(2*s+1)*64 + rp] = pkrtz(p.z, p.w);
            }
        }
        __syncthreads();

        // prefetch next chunk
        if (ck < 3){
            preZ[0] = *(const float4*)(gz + (ck+1)*64);
            preZ[1] = *(const float4*)(gz + (ck+1)*64 + 32);
#pragma unroll
            for (int u2 = 0; u2 < 4; ++u2)
                preP[u2] = *(const float4*)(gp + (ck+1)*64 + 16*u2);
        }

        // ---- l1 hot loop: per-chunk f16 packed accumulators ----
        h2 acc[2][4];
#pragma unroll
        for (int j = 0; j < 2; ++j)
#pragma unroll
            for (int i = 0; i < 4; ++i) acc[j][i] = (h2)(_Float16)0.f;

#pragma unroll 4
        for (int k2 = 0; k2 < 32; ++k2){
            uint4 aw = *(const uint4*)&stgZ[k2*32 + 4*tn];
            uint2 bw = *(const uint2*)&stgP[k2*64 + 2*tm];
            h2 a[4] = {bch2(aw.x), bch2(aw.y), bch2(aw.z), bch2(aw.w)};
            h2 b[2] = {bch2(bw.x), bch2(bw.y)};
#pragma unroll
            for (int j = 0; j < 2; ++j)
#pragma unroll
                for (int i = 0; i < 4; ++i){
                    h2 d = a[i] - b[j];
                    acc[j][i] = acc[j][i] + habs2(d);
                }
        }
        // flush chunk partials to f32
#pragma unroll
        for (int j = 0; j < 2; ++j)
#pragma unroll
            for (int i = 0; i < 4; ++i)
                l1f[j][i] += (float)acc[j][i][0] + (float)acc[j][i][1];

        // ---- dp via MFMA (2 ksteps of 32) ----
        {
            const int an0  = lane & 15;
            const int koff = (lane >> 4) * 4;
            const int bm0  = 16 * w + (lane & 15);
#pragma unroll
            for (int ks = 0; ks < 2; ++ks){
                const int k2b = 16 * ks + koff;
                u32 b0 = stgP[(k2b+0)*64 + bm0];
                u32 b1 = stgP[(k2b+1)*64 + bm0];
                u32 b2 = stgP[(k2b+2)*64 + bm0];
                u32 b3 = stgP[(k2b+3)*64 + bm0];
                h8 bf = __builtin_bit_cast(h8, make_uint4(b0, b1, b2, b3));
#pragma unroll
                for (int tt = 0; tt < 2; ++tt){
                    const int an = 16 * tt + an0;
                    u32 a0 = stgZ[(k2b+0)*32 + an];
                    u32 a1 = stgZ[(k2b+1)*32 + an];
                    u32 a2 = stgZ[(k2b+2)*32 + an];
                    u32 a3 = stgZ[(k2b+3)*32 + an];
                    h8 af = __builtin_bit_cast(h8, make_uint4(a0, a1, a2, a3));
                    dpacc[tt] = __builtin_amdgcn_mfma_f32_16x16x32_f16(af, bf, dpacc[tt], 0, 0, 0);
                }
            }
        }

        // ---- norm mini-pass over this chunk ----
        if (q < 128){
#pragma unroll
            for (int i = 0; i < 8; ++i){
                h2 x = bch2(stgZ[(8*noct + i)*32 + nrow_z]);
                float x0 = (float)x[0], x1 = (float)x[1];
                nzacc += x0*x0 + x1*x1;
            }
        } else {
#pragma unroll
            for (int i = 0; i < 16; ++i){
                h2 x = bch2(stgP[(16*nhalf + i)*64 + nrow_p]);
                float x0 = (float)x[0], x1 = (float)x[1];
                npacc += x0*x0 + x1*x1;
            }
        }
        __syncthreads();
    }

    // ---- epilogue (staging regions reused) ----
    float* dpL = (float*)smem;              // [2][32][65]
    float* l1b = (float*)(smem + 4224);     // [256][8]
    float* nzp = (float*)(smem + 6272);     // [8][32]
    float* npp = (float*)(smem + 6528);     // [4][64]
    float* nzf = (float*)(smem + 6784);     // [32]
    float* npf = (float*)(smem + 6816);     // [64]

    {
        const int mwr = 16 * w + (lane & 15);
        const int nq  = (lane >> 4) * 4;
#pragma unroll
        for (int tt = 0; tt < 2; ++tt)
#pragma unroll
            for (int r = 0; r < 4; ++r)
                dpL[(g*32 + 16*tt + nq + r)*65 + mwr] = dpacc[tt][r];
    }
    if (q < 128) nzp[(g*4 + noct)*32 + nrow_z] = nzacc;
    else         npp[(g*2 + nhalf)*64 + nrow_p] = npacc;
    if (g == 1){
        float* dst = l1b + q * 8;
        *(float4*)(dst)     = make_float4(l1f[0][0], l1f[0][1], l1f[0][2], l1f[0][3]);
        *(float4*)(dst + 4) = make_float4(l1f[1][0], l1f[1][1], l1f[1][2], l1f[1][3]);
    }
    __syncthreads();

    if (t < 32){
        float s = 0.f;
#pragma unroll
        for (int u2 = 0; u2 < 8; ++u2) s += nzp[u2*32 + t];
        nzf[t] = s;
    } else if (t < 96){
        float s = 0.f;
#pragma unroll
        for (int u2 = 0; u2 < 4; ++u2) s += npp[u2*64 + (t - 32)];
        npf[t - 32] = s;
    }
    __syncthreads();

    if (g == 0){
        const float* src = l1b + q * 8;
        float4 p0 = *(const float4*)(src);
        float4 p1 = *(const float4*)(src + 4);
        float l1o[2][4];
        l1o[0][0] = l1f[0][0] + p0.x; l1o[0][1] = l1f[0][1] + p0.y;
        l1o[0][2] = l1f[0][2] + p0.z; l1o[0][3] = l1f[0][3] + p0.w;
        l1o[1][0] = l1f[1][0] + p1.x; l1o[1][1] = l1f[1][1] + p1.y;
        l1o[1][2] = l1f[1][2] + p1.z; l1o[1][3] = l1f[1][3] + p1.w;

        float nzv[4];
        float4 nz4 = *(const float4*)&nzf[4*tn];
        nzv[0] = nz4.x; nzv[1] = nz4.y; nzv[2] = nz4.z; nzv[3] = nz4.w;

        const int n0g = n_base + 4 * tn;
#pragma unroll
        for (int j = 0; j < 2; ++j){
            const int m = 2 * tm + j;
            const float npv = npf[m];
            float l2v[4], dpv[4];
#pragma unroll
            for (int i = 0; i < 4; ++i){
                const float dp = dpL[(4*tn + i)*65 + m] + dpL[(32 + 4*tn + i)*65 + m];
                dpv[i] = dp;
                const float l2sq = nzv[i] + npv - 2.f * dp;
                l2v[i] = sqrtf(fmaxf(l2sq, 0.f));
            }
            float* op = out + ((size_t)(m_base + m) * 1024 + n0g) * 3;
            ((float4*)op)[0] = make_float4(l1o[j][0], l2v[0], dpv[0], l1o[j][1]);
            ((float4*)op)[1] = make_float4(l2v[1],    dpv[1], l1o[j][2], l2v[2]);
            ((float4*)op)[2] = make_float4(dpv[2],    l1o[j][3], l2v[3], dpv[3]);
        }
    }
}

extern "C" void kernel_launch(void* const* d_in, const int* in_sizes, int n_in,
                              void* d_out, int out_size, void* d_ws, size_t ws_size,
                              hipStream_t stream) {
    const float* z   = (const float*)d_in[0];
    const float* zpr = (const float*)d_in[1];
    float* out = (float*)d_out;
    fused_kernel<<<512, 512, 0, stream>>>(z, zpr, out);
}